// Round 3
// baseline (163.792 us; speedup 1.0000x reference)
//
#include <hip/hip_runtime.h>
#include <math.h>

// Problem constants: B,C,H,W = 32,64,64,64; K=1024
constexpr int Cc  = 64;
constexpr int Kc  = 1024;
constexpr int HW  = 4096;
constexpr int CHW = Cc * HW;          // 262144
constexpr int Nrows = 131072;
constexpr int TOTAL = 8388608;
constexpr int ROWS  = 128;            // rows per block
constexpr int NBLK  = Nrows / ROWS;   // 1024 blocks

typedef __attribute__((ext_vector_type(8))) short short8;   // 8 bf16
typedef __attribute__((ext_vector_type(4))) float f32x4;

union U4S8 { uint4 u; short8 s; };

__device__ __forceinline__ unsigned bf16pair(float a, float b) {
    // pack RNE(a) in low 16, RNE(b) in high 16
    unsigned ua = __float_as_uint(a), ub = __float_as_uint(b);
    ua = (ua + 0x7FFFu + ((ua >> 16) & 1u)) >> 16;
    ub = (ub + 0x7FFFu + ((ub >> 16) & 1u)) & 0xFFFF0000u;
    return ua | ub;
}

__device__ __forceinline__ unsigned short bf16_rne(float x) {
    unsigned u = __float_as_uint(x);
    return (unsigned short)((u + 0x7FFFu + ((u >> 16) & 1u)) >> 16);
}

// ---------------------------------------------------------------------------
// Prep: e2p[k] = 1 + ||e_k||^2 ; codebook -> bf16 B-fragment order; also
// zero counts/sse (replaces the memset graph node).
//   cbB[((ct*2+ks)*64 + quad*16 + n)*8 + j] = bf16(cb[ct*16+n][ks*32+quad*8+j])
// ---------------------------------------------------------------------------
__global__ void prep_kernel(const float* __restrict__ cb,
                            float* __restrict__ e2p,
                            unsigned short* __restrict__ cbB,
                            unsigned int* __restrict__ counts,
                            float* __restrict__ sse) {
    int k = blockIdx.x;          // code 0..1023
    int c = threadIdx.x;         // dim  0..63
    float v = cb[k * Cc + c];
    float s = v * v;
    #pragma unroll
    for (int off = 32; off; off >>= 1) s += __shfl_down(s, off);
    if (c == 0) {
        e2p[k] = 1.0f + s;
        counts[k] = 0u;
        if (k == 0) *sse = 0.f;
    }
    int ct = k >> 4, n = k & 15;
    int ks = c >> 5, quad = (c >> 3) & 3, j = c & 7;
    cbB[(((ct * 2 + ks) * 64) + quad * 16 + n) * 8 + j] = bf16_rne(v);
}

// ---------------------------------------------------------------------------
// Main: 1024 blocks x 256 threads; block = 128 rows. Wave w handles ALL 128
// rows x code-tiles [w*16, w*16+16)  (disjoint B across waves -> block reads
// the 128 KB bf16 codebook exactly once). Per-row argmin packed as
// (bits(d') & ~1023) | code  with d' = 1 + ||e||^2 - 2 x.e  in (0.5,2).
// Cross-wave combine via LDS (4 candidates/row, u32 min).
// ---------------------------------------------------------------------------
__global__ __launch_bounds__(256) void vq_main(
        const float* __restrict__ inp,
        const float* __restrict__ cb,        // fp32 codebook (epilogue gather)
        const float* __restrict__ e2p,
        const uint4* __restrict__ cbB4,      // bf16 codebook, B-frag order
        float* __restrict__ qout,
        unsigned int* __restrict__ counts,
        float* __restrict__ sse_out) {
    __shared__ uint4 lds_a[ROWS * 8];       // 16 KB: 128 rows x 8 chunks(16B)
    __shared__ float lds_e2p[Kc];           // 4 KB
    __shared__ unsigned lds_res[ROWS * 4];  // 2 KB: [row*4 + wave]
    __shared__ float lds_x2[256];           // 1 KB

    const int tid = threadIdx.x;
    const int b   = blockIdx.x >> 5;        // 32 blocks per batch image
    const int hw0 = (blockIdx.x & 31) << 7; // 128 hw per block
    const int r     = tid & 127;
    const int chalf = tid >> 7;             // which 32-channel half
    const float* xp = inp + b * CHW + hw0 + r + chalf * 32 * HW;

    // ---- stage A ([c][hw] -> [row][c] bf16, swizzled) + ||x||^2 partial ----
    float x2 = 0.f;
    #pragma unroll
    for (int q = 0; q < 4; ++q) {
        float v0 = xp[(q * 8 + 0) * HW], v1 = xp[(q * 8 + 1) * HW];
        float v2 = xp[(q * 8 + 2) * HW], v3 = xp[(q * 8 + 3) * HW];
        float v4 = xp[(q * 8 + 4) * HW], v5 = xp[(q * 8 + 5) * HW];
        float v6 = xp[(q * 8 + 6) * HW], v7 = xp[(q * 8 + 7) * HW];
        x2 = fmaf(v0, v0, x2); x2 = fmaf(v1, v1, x2);
        x2 = fmaf(v2, v2, x2); x2 = fmaf(v3, v3, x2);
        x2 = fmaf(v4, v4, x2); x2 = fmaf(v5, v5, x2);
        x2 = fmaf(v6, v6, x2); x2 = fmaf(v7, v7, x2);
        uint4 p;
        p.x = bf16pair(v0, v1); p.y = bf16pair(v2, v3);
        p.z = bf16pair(v4, v5); p.w = bf16pair(v6, v7);
        int ch = chalf * 4 + q;
        lds_a[r * 8 + (ch ^ (r & 7))] = p;
    }
    lds_x2[tid] = x2;
    #pragma unroll
    for (int i = 0; i < 4; ++i) lds_e2p[tid + 256 * i] = e2p[tid + 256 * i];
    __syncthreads();

    const int lane = tid & 63, w = tid >> 6;
    const int col = lane & 15, quad = lane >> 4;

    // ---- A fragments for all 8 row-tiles (live in regs for whole loop) ----
    short8 af[8][2];
    #pragma unroll
    for (int mi = 0; mi < 8; ++mi) {
        int row = mi * 16 + col;
        #pragma unroll
        for (int ks = 0; ks < 2; ++ks) {
            U4S8 t; t.u = lds_a[row * 8 + ((ks * 4 + quad) ^ (row & 7))];
            af[mi][ks] = t.s;
        }
    }

    unsigned best[8][4];
    #pragma unroll
    for (int mi = 0; mi < 8; ++mi)
        #pragma unroll
        for (int e = 0; e < 4; ++e) best[mi][e] = 0xFFFFFFFFu;

    // ---- 16 code tiles for this wave ----
    const int base = w * 16;
    uint4 nb0 = cbB4[base * 128 + lane];
    uint4 nb1 = cbB4[base * 128 + 64 + lane];
    #pragma unroll 4
    for (int i = 0; i < 16; ++i) {
        U4S8 t0, t1; t0.u = nb0; t1.u = nb1;
        int ct = base + i;
        float e2v = lds_e2p[ct * 16 + col];
        int nct = base + ((i + 1) & 15);       // wrap: always in-bounds
        nb0 = cbB4[nct * 128 + lane];
        nb1 = cbB4[nct * 128 + 64 + lane];
        unsigned code = (unsigned)(ct * 16 + col);
        #pragma unroll
        for (int mi = 0; mi < 8; ++mi) {
            f32x4 acc = {0.f, 0.f, 0.f, 0.f};
            acc = __builtin_amdgcn_mfma_f32_16x16x32_bf16(af[mi][0], t0.s, acc, 0, 0, 0);
            acc = __builtin_amdgcn_mfma_f32_16x16x32_bf16(af[mi][1], t1.s, acc, 0, 0, 0);
            #pragma unroll
            for (int e = 0; e < 4; ++e) {
                float d = fmaf(-2.0f, acc[e], e2v);
                unsigned p = (__float_as_uint(d) & 0xFFFFFC00u) | code;
                best[mi][e] = best[mi][e] < p ? best[mi][e] : p;
            }
        }
    }

    // ---- reduce across the 16 cols; post wave-candidate per row ----
    #pragma unroll
    for (int mi = 0; mi < 8; ++mi) {
        #pragma unroll
        for (int e = 0; e < 4; ++e) {
            unsigned v = best[mi][e];
            #pragma unroll
            for (int m = 1; m < 16; m <<= 1) {
                unsigned o = (unsigned)__shfl_xor((int)v, m);
                v = v < o ? v : o;
            }
            if (col == e) lds_res[(mi * 16 + quad * 4 + e) * 4 + w] = v;
        }
    }
    __syncthreads();

    // ---- epilogue: thread pair (r, r+128) owns row r ----
    const uint4 cand = *reinterpret_cast<const uint4*>(&lds_res[r * 4]);
    unsigned v01 = cand.x < cand.y ? cand.x : cand.y;
    unsigned v23 = cand.z < cand.w ? cand.z : cand.w;
    unsigned v = v01 < v23 ? v01 : v23;
    int idx = (int)(v & 1023u);
    float dm1 = __uint_as_float(v & 0xFFFFFC00u) - 1.0f;  // e2 - 2x.e
    float ssep = lds_x2[tid] + 0.5f * dm1;  // pair-sum = ||x||^2 + dm1
    if (tid < 128) atomicAdd(&counts[idx], 1u);

    const float4* qv = reinterpret_cast<const float4*>(cb + idx * Cc) + chalf * 8;
    float* op = qout + b * CHW + hw0 + r + chalf * 32 * HW;
    #pragma unroll
    for (int q4 = 0; q4 < 8; ++q4) {
        float4 qq = qv[q4];
        op[(q4 * 4 + 0) * HW] = qq.x;
        op[(q4 * 4 + 1) * HW] = qq.y;
        op[(q4 * 4 + 2) * HW] = qq.z;
        op[(q4 * 4 + 3) * HW] = qq.w;
    }
    #pragma unroll
    for (int off = 32; off; off >>= 1) ssep += __shfl_down(ssep, off);
    if (lane == 0) atomicAdd(sse_out, ssep);
}

// ---------------------------------------------------------------------------
__global__ void finalize_kernel(const unsigned int* __restrict__ counts,
                                const float* __restrict__ sse,
                                const float* __restrict__ beta,
                                float* __restrict__ loss_out,
                                float* __restrict__ perp_out) {
    __shared__ float red[16];
    int t = threadIdx.x;                  // 0..1023 == K
    float p = (float)counts[t] * (1.0f / (float)Nrows);
    float s = p * logf(p + 1e-10f);
    #pragma unroll
    for (int off = 32; off; off >>= 1) s += __shfl_down(s, off);
    if ((t & 63) == 0) red[t >> 6] = s;
    __syncthreads();
    if (t == 0) {
        float tot = 0.f;
        #pragma unroll
        for (int i = 0; i < 16; ++i) tot += red[i];
        *perp_out = expf(-tot);
        *loss_out = (1.0f + *beta) * (*sse) * (1.0f / (float)TOTAL);
    }
}

// ---------------------------------------------------------------------------
// Workspace layout (bytes):
//   [0, 4096)        counts (1024 u32)     -- zeroed by prep
//   [4096, 4100)     sse (1 f32)           -- zeroed by prep
//   [8192, 12288)    e2p (1024 f32)
//   [12288, 143360)  cbB bf16 B-frag order (64 tiles x 2 KB)
// ---------------------------------------------------------------------------
extern "C" void kernel_launch(void* const* d_in, const int* in_sizes, int n_in,
                              void* d_out, int out_size, void* d_ws, size_t ws_size,
                              hipStream_t stream) {
    const float* inp  = (const float*)d_in[0];
    const float* cb   = (const float*)d_in[1];
    const float* beta = (const float*)d_in[2];

    float* loss = (float*)d_out;
    float* qout = loss + 1;
    float* perp = loss + 1 + TOTAL;

    char* ws = (char*)d_ws;
    unsigned int* counts = (unsigned int*)ws;
    float* sse  = (float*)(ws + 4096);
    float* e2p  = (float*)(ws + 8192);
    unsigned short* cbB = (unsigned short*)(ws + 12288);

    prep_kernel<<<Kc, 64, 0, stream>>>(cb, e2p, cbB, counts, sse);
    vq_main<<<NBLK, 256, 0, stream>>>(inp, cb, e2p, (const uint4*)cbB,
                                      qout, counts, sse);
    finalize_kernel<<<1, Kc, 0, stream>>>(counts, sse, beta, loss, perp);
}